// Round 4
// baseline (403.127 us; speedup 1.0000x reference)
//
#include <hip/hip_runtime.h>
#include <hip/hip_bf16.h>

#define S_LEN 2048
#define HIDN  2048
#define NH    16
#define NKV   8
#define DH    128

typedef __bf16 bf16_t;
typedef __bf16 bf16x8 __attribute__((ext_vector_type(8)));
typedef float  floatx4 __attribute__((ext_vector_type(4)));

#define NEG_BIG (-1.0e30f)

#define BM 128
#define BN 128
#define BK 64

// ---------------- f32 -> bf16 input conversion ----------------
__global__ void cvt_kernel(const float* __restrict__ src, bf16_t* __restrict__ dst, int n)
{
  const int base = blockIdx.x * 4096 + threadIdx.x;
  #pragma unroll
  for (int i = 0; i < 16; ++i) {
    int idx = base + i * 256;
    if (idx < n) dst[idx] = (bf16_t)src[idx];
  }
}

// ---------------- GEMM tile (m93 structure, through-VGPR staging) ----------------
// C[m0+..][n0+..] = A[M,K] * Bt[N,K]^T, both row-major with row stride K.
// gfx950 16x16x32 bf16 fragment layouts (m89/m91-verified):
//   A-frag: m = lane&15, k = (lane>>4)*8 + j   (8 contiguous bf16)
//   B-frag: n = lane&15, k = (lane>>4)*8 + j   (B^T rows, 8 contiguous bf16)
//   C/D   : col = lane&15, row = (lane>>4)*4 + reg
__device__ __forceinline__ void gemm_tile(
    const bf16_t* __restrict__ A, const bf16_t* __restrict__ Bt,
    int K, int m0, int n0, floatx4 acc[4][4], bf16_t* As, bf16_t* Bs)
{
  const int tid  = threadIdx.x;
  const int lane = tid & 63;
  const int wave = tid >> 6;
  const int wm = (wave & 1) << 6;
  const int wn = (wave >> 1) << 6;
  const int lr = lane & 15;
  const int lq = lane >> 4;

  #pragma unroll
  for (int i = 0; i < 4; ++i)
    #pragma unroll
    for (int j = 0; j < 4; ++j)
      acc[i][j] = floatx4{0.f, 0.f, 0.f, 0.f};

  bf16x8 ra[4], rb[4];
  auto ld = [&](int k0) {
    #pragma unroll
    for (int it = 0; it < 4; ++it) {
      int linear = it * 256 + tid;          // 0..1023
      int row = linear >> 3;                // 128 rows
      int c8  = linear & 7;                 // 8 x 16B chunks per row (BK=64)
      ra[it] = *(const bf16x8*)(A  + (size_t)(m0 + row) * K + k0 + c8 * 8);
      rb[it] = *(const bf16x8*)(Bt + (size_t)(n0 + row) * K + k0 + c8 * 8);
    }
  };
  ld(0);

  for (int k0 = 0; k0 < K; k0 += BK) {
    #pragma unroll
    for (int it = 0; it < 4; ++it) {
      int linear = it * 256 + tid;
      *(bf16x8*)(As + linear * 8) = ra[it];
      *(bf16x8*)(Bs + linear * 8) = rb[it];
    }
    __syncthreads();                         // staging visible
    if (k0 + BK < K) ld(k0 + BK);            // prefetch next chunk
    #pragma unroll
    for (int kk = 0; kk < BK; kk += 32) {
      bf16x8 af[4], bfr[4];
      #pragma unroll
      for (int t = 0; t < 4; ++t) {
        af[t]  = *(const bf16x8*)(As + (wm + t * 16 + lr) * BK + kk + lq * 8);
        bfr[t] = *(const bf16x8*)(Bs + (wn + t * 16 + lr) * BK + kk + lq * 8);
      }
      #pragma unroll
      for (int i = 0; i < 4; ++i)
        #pragma unroll
        for (int j = 0; j < 4; ++j)
          acc[i][j] = __builtin_amdgcn_mfma_f32_16x16x32_bf16(af[i], bfr[j], acc[i][j], 0, 0, 0);
    }
    __syncthreads();                         // compute done before next store
  }
}

__global__ void __launch_bounds__(256, 2) gemm_qkv_kernel(
    const bf16_t* __restrict__ x, const bf16_t* __restrict__ Wq,
    const bf16_t* __restrict__ Wk, const bf16_t* __restrict__ Wv,
    bf16_t* __restrict__ qb, bf16_t* __restrict__ kb, bf16_t* __restrict__ vb)
{
  __shared__ __align__(16) bf16_t As[BM * BK];
  __shared__ __align__(16) bf16_t Bs[BN * BK];
  const int m0 = blockIdx.x * BM;
  const int nt = blockIdx.y;                 // 0..31 over combined N=4096
  const bf16_t* Bt;
  bf16_t* outp;
  int hbase;
  if (nt < 16)      { Bt = Wq + (size_t)nt * 128 * HIDN;        outp = qb; hbase = nt; }
  else if (nt < 24) { Bt = Wk + (size_t)(nt - 16) * 128 * HIDN; outp = kb; hbase = nt - 16; }
  else              { Bt = Wv + (size_t)(nt - 24) * 128 * HIDN; outp = vb; hbase = nt - 24; }

  floatx4 acc[4][4];
  gemm_tile(x, Bt, HIDN, m0, 0, acc, As, Bs);

  const int lane = threadIdx.x & 63, wave = threadIdx.x >> 6;
  const int wm = (wave & 1) << 6, wn = (wave >> 1) << 6;
  const int lr = lane & 15, lq = lane >> 4;
  #pragma unroll
  for (int i = 0; i < 4; ++i)
    #pragma unroll
    for (int j = 0; j < 4; ++j)
      #pragma unroll
      for (int r = 0; r < 4; ++r) {
        int srow = m0 + wm + i * 16 + lq * 4 + r;
        int d    = wn + j * 16 + lr;          // tile spans exactly one head
        outp[((size_t)hbase * S_LEN + srow) * DH + d] = (bf16_t)acc[i][j][r];
      }
}

// out = ctx[2048,2048] * Wo^T -> d_out (float32)
__global__ void __launch_bounds__(256, 2) gemm_out_kernel(
    const bf16_t* __restrict__ ctx, const bf16_t* __restrict__ Wo,
    float* __restrict__ out)
{
  __shared__ __align__(16) bf16_t As[BM * BK];
  __shared__ __align__(16) bf16_t Bs[BN * BK];
  const int m0 = blockIdx.x * BM;
  const int n0 = blockIdx.y * BN;
  floatx4 acc[4][4];
  gemm_tile(ctx, Wo, HIDN, m0, n0, acc, As, Bs);

  const int lane = threadIdx.x & 63, wave = threadIdx.x >> 6;
  const int wm = (wave & 1) << 6, wn = (wave >> 1) << 6;
  const int lr = lane & 15, lq = lane >> 4;
  #pragma unroll
  for (int i = 0; i < 4; ++i)
    #pragma unroll
    for (int j = 0; j < 4; ++j)
      #pragma unroll
      for (int r = 0; r < 4; ++r) {
        int srow = m0 + wm + i * 16 + lq * 4 + r;
        int col  = n0 + wn + j * 16 + lr;
        out[(size_t)srow * HIDN + col] = acc[i][j][r];
      }
}

// In-place rotate-half RoPE on q and k using the provided f32 tables.
// cos[s][d+64] == cos[s][d] (table is concat([freqs, freqs])).
__global__ void rope_kernel(bf16_t* __restrict__ qb, bf16_t* __restrict__ kb,
                            const float* __restrict__ cosT, const float* __restrict__ sinT)
{
  const int NQ = NH * S_LEN * 64;            // 2^21
  const int NK = NKV * S_LEN * 64;           // 2^20
  int idx = blockIdx.x * 256 + threadIdx.x;
  if (idx >= NQ + NK) return;
  bf16_t* base = qb;
  int rem = idx;
  if (idx >= NQ) { base = kb; rem = idx - NQ; }
  int d  = rem & 63;
  int s  = (rem >> 6) & (S_LEN - 1);
  int hh = rem >> 17;
  size_t off = ((size_t)hh * S_LEN + s) * DH;
  float c  = cosT[s * DH + d];
  float sn = sinT[s * DH + d];
  float a = (float)base[off + d];
  float b = (float)base[off + d + 64];
  base[off + d]      = (bf16_t)(a * c - b * sn);
  base[off + d + 64] = (bf16_t)(b * c + a * sn);
}

// v[hkv][s][d] -> vt[hkv][d][s]
__global__ void vtrans_kernel(const bf16_t* __restrict__ vb, bf16_t* __restrict__ vtb)
{
  __shared__ bf16_t tile[64][65];
  const int hkv = blockIdx.z;
  const int s0 = blockIdx.x * 64;
  const int d0 = blockIdx.y * 64;
  const int r = threadIdx.x >> 2;
  const int c = (threadIdx.x & 3) * 16;
  const bf16_t* src = vb + (size_t)hkv * S_LEN * DH;
  #pragma unroll
  for (int u = 0; u < 16; ++u)
    tile[r][c + u] = src[(size_t)(s0 + r) * DH + d0 + c + u];
  __syncthreads();
  bf16_t* dst = vtb + (size_t)hkv * DH * S_LEN;
  #pragma unroll
  for (int u = 0; u < 16; ++u)
    dst[(size_t)(d0 + r) * S_LEN + s0 + c + u] = tile[c + u][r];
}

// Flash attention: one block per (q-tile of 128, head). 4 waves in 2x2 over 128x128.
__global__ void __launch_bounds__(256, 1) attn_kernel(
    const bf16_t* __restrict__ qb, const bf16_t* __restrict__ kb,
    const bf16_t* __restrict__ vtb, bf16_t* __restrict__ ctx)
{
  __shared__ __align__(16) bf16_t Qs[128 * 128];
  __shared__ __align__(16) bf16_t KPs[128 * 128];
  __shared__ __align__(16) bf16_t Vts[128 * 128];
  __shared__ float mpart[2][128];
  __shared__ float lpart[2][128];
  __shared__ float Mrow[128];
  __shared__ float Lrow[128];

  const int h   = blockIdx.y;
  const int qt  = blockIdx.x;
  const int hkv = h >> 1;
  const int q0  = qt * 128;

  const int tid = threadIdx.x;
  const int lane = tid & 63, wave = tid >> 6;
  const int wm = (wave & 1) << 6, wn = (wave >> 1) << 6;
  const int lr = lane & 15, lq = lane >> 4;
  const int wnidx = wave >> 1;

  const bf16_t* qbase  = qb  + ((size_t)h * S_LEN + q0) * DH;
  const bf16_t* kbase  = kb  + (size_t)hkv * S_LEN * DH;
  const bf16_t* vtbase = vtb + (size_t)hkv * DH * S_LEN;

  {
    bf16x8 rq[8];
    #pragma unroll
    for (int it = 0; it < 8; ++it) {
      int linear = it * 256 + tid;
      rq[it] = *(const bf16x8*)(qbase + (size_t)linear * 8);
    }
    #pragma unroll
    for (int it = 0; it < 8; ++it) {
      int linear = it * 256 + tid;
      *(bf16x8*)(Qs + linear * 8) = rq[it];
    }
  }
  if (tid < 128) { Mrow[tid] = NEG_BIG; Lrow[tid] = 0.f; }

  floatx4 o[4][4];
  #pragma unroll
  for (int i = 0; i < 4; ++i)
    #pragma unroll
    for (int j = 0; j < 4; ++j)
      o[i][j] = floatx4{0.f, 0.f, 0.f, 0.f};

  const float scale = 0.08838834764831845f;  // 1/sqrt(128)

  for (int cc = 0; cc <= qt; ++cc) {
    const int kv0 = cc * 128;
    __syncthreads();
    {
      bf16x8 rk[8], rv[8];
      #pragma unroll
      for (int it = 0; it < 8; ++it) {
        int linear = it * 256 + tid;
        int row = linear >> 4, c8 = linear & 15;
        rk[it] = *(const bf16x8*)(kbase  + (size_t)(kv0 + row) * DH + c8 * 8);
        rv[it] = *(const bf16x8*)(vtbase + (size_t)row * S_LEN + kv0 + c8 * 8);
      }
      #pragma unroll
      for (int it = 0; it < 8; ++it) {
        int linear = it * 256 + tid;
        *(bf16x8*)(KPs + linear * 8) = rk[it];
        *(bf16x8*)(Vts + linear * 8) = rv[it];
      }
    }
    __syncthreads();

    floatx4 sacc[4][4];
    #pragma unroll
    for (int i = 0; i < 4; ++i)
      #pragma unroll
      for (int j = 0; j < 4; ++j)
        sacc[i][j] = floatx4{0.f, 0.f, 0.f, 0.f};
    #pragma unroll
    for (int kk = 0; kk < 4; ++kk) {
      bf16x8 af[4], bfr[4];
      #pragma unroll
      for (int t = 0; t < 4; ++t) {
        af[t]  = *(const bf16x8*)(Qs  + (wm + t * 16 + lr) * 128 + kk * 32 + lq * 8);
        bfr[t] = *(const bf16x8*)(KPs + (wn + t * 16 + lr) * 128 + kk * 32 + lq * 8);
      }
      #pragma unroll
      for (int i = 0; i < 4; ++i)
        #pragma unroll
        for (int j = 0; j < 4; ++j)
          sacc[i][j] = __builtin_amdgcn_mfma_f32_16x16x32_bf16(af[i], bfr[j], sacc[i][j], 0, 0, 0);
    }

    #pragma unroll
    for (int i = 0; i < 4; ++i)
      #pragma unroll
      for (int j = 0; j < 4; ++j)
        #pragma unroll
        for (int r = 0; r < 4; ++r) {
          int rowg = q0 + wm + i * 16 + lq * 4 + r;
          int colg = kv0 + wn + j * 16 + lr;
          float v = sacc[i][j][r] * scale;
          sacc[i][j][r] = (colg <= rowg) ? v : NEG_BIG;
        }

    float rmax[4][4];
    #pragma unroll
    for (int i = 0; i < 4; ++i)
      #pragma unroll
      for (int r = 0; r < 4; ++r) {
        float v = fmaxf(fmaxf(sacc[i][0][r], sacc[i][1][r]),
                        fmaxf(sacc[i][2][r], sacc[i][3][r]));
        #pragma unroll
        for (int md = 1; md < 16; md <<= 1) v = fmaxf(v, __shfl_xor(v, md, 64));
        rmax[i][r] = v;
      }
    if (lr == 0) {
      #pragma unroll
      for (int i = 0; i < 4; ++i)
        #pragma unroll
        for (int r = 0; r < 4; ++r)
          mpart[wnidx][wm + i * 16 + lq * 4 + r] = rmax[i][r];
    }
    __syncthreads();

    float mnew[4][4], alphav[4][4], lsum[4][4];
    #pragma unroll
    for (int i = 0; i < 4; ++i)
      #pragma unroll
      for (int r = 0; r < 4; ++r) {
        int row = wm + i * 16 + lq * 4 + r;
        float mc = fmaxf(mpart[0][row], mpart[1][row]);
        float mo = Mrow[row];
        float mn = fmaxf(mo, mc);
        mnew[i][r] = mn;
        alphav[i][r] = __expf(mo - mn);
        lsum[i][r] = 0.f;
      }
    #pragma unroll
    for (int i = 0; i < 4; ++i)
      #pragma unroll
      for (int j = 0; j < 4; ++j)
        #pragma unroll
        for (int r = 0; r < 4; ++r) {
          float p = __expf(sacc[i][j][r] - mnew[i][r]);
          lsum[i][r] += p;
          int row = wm + i * 16 + lq * 4 + r;
          int col = wn + j * 16 + lr;
          KPs[row * 128 + col] = (bf16_t)p;
        }
    #pragma unroll
    for (int i = 0; i < 4; ++i)
      #pragma unroll
      for (int r = 0; r < 4; ++r) {
        float v = lsum[i][r];
        #pragma unroll
        for (int md = 1; md < 16; md <<= 1) v += __shfl_xor(v, md, 64);
        if (lr == 0) lpart[wnidx][wm + i * 16 + lq * 4 + r] = v;
      }
    __syncthreads();

    if (wnidx == 0 && lr == 0) {
      #pragma unroll
      for (int i = 0; i < 4; ++i)
        #pragma unroll
        for (int r = 0; r < 4; ++r) {
          int row = wm + i * 16 + lq * 4 + r;
          Lrow[row] = Lrow[row] * alphav[i][r] + lpart[0][row] + lpart[1][row];
          Mrow[row] = mnew[i][r];
        }
    }

    #pragma unroll
    for (int i = 0; i < 4; ++i)
      #pragma unroll
      for (int j = 0; j < 4; ++j)
        #pragma unroll
        for (int r = 0; r < 4; ++r)
          o[i][j][r] *= alphav[i][r];
    #pragma unroll
    for (int kk = 0; kk < 4; ++kk) {
      bf16x8 af[4], bfr[4];
      #pragma unroll
      for (int t = 0; t < 4; ++t) {
        af[t]  = *(const bf16x8*)(KPs + (wm + t * 16 + lr) * 128 + kk * 32 + lq * 8);
        bfr[t] = *(const bf16x8*)(Vts + (wn + t * 16 + lr) * 128 + kk * 32 + lq * 8);
      }
      #pragma unroll
      for (int i = 0; i < 4; ++i)
        #pragma unroll
        for (int j = 0; j < 4; ++j)
          o[i][j] = __builtin_amdgcn_mfma_f32_16x16x32_bf16(af[i], bfr[j], o[i][j], 0, 0, 0);
    }
  }

  __syncthreads();
  #pragma unroll
  for (int i = 0; i < 4; ++i) {
    float inv[4];
    #pragma unroll
    for (int r = 0; r < 4; ++r) inv[r] = 1.0f / Lrow[wm + i * 16 + lq * 4 + r];
    #pragma unroll
    for (int j = 0; j < 4; ++j)
      #pragma unroll
      for (int r = 0; r < 4; ++r) {
        int srow = q0 + wm + i * 16 + lq * 4 + r;
        int col  = h * DH + wn + j * 16 + lr;
        ctx[(size_t)srow * HIDN + col] = (bf16_t)(o[i][j][r] * inv[r]);
      }
  }
}

extern "C" void kernel_launch(void* const* d_in, const int* in_sizes, int n_in,
                              void* d_out, int out_size, void* d_ws, size_t ws_size,
                              hipStream_t stream)
{
  const float* xf   = (const float*)d_in[0];
  const float* Wqf  = (const float*)d_in[1];
  const float* Wkf  = (const float*)d_in[2];
  const float* Wvf  = (const float*)d_in[3];
  const float* Wof  = (const float*)d_in[4];
  const float* cosT = (const float*)d_in[5];
  const float* sinT = (const float*)d_in[6];
  float* out = (float*)d_out;

  char* ws = (char*)d_ws;
  const size_t MB = 1u << 20;
  bf16_t* xc  = (bf16_t*)(ws);              // 8 MB
  bf16_t* Wqc = (bf16_t*)(ws + 8  * MB);    // 8 MB
  bf16_t* Wkc = (bf16_t*)(ws + 16 * MB);    // 4 MB
  bf16_t* Wvc = (bf16_t*)(ws + 20 * MB);    // 4 MB
  bf16_t* Woc = (bf16_t*)(ws + 24 * MB);    // 8 MB
  bf16_t* qb  = (bf16_t*)(ws + 32 * MB);    // 8 MB
  bf16_t* kb  = (bf16_t*)(ws + 40 * MB);    // 4 MB
  bf16_t* vb  = (bf16_t*)(ws + 44 * MB);    // 4 MB
  bf16_t* vtb = (bf16_t*)(ws + 48 * MB);    // 4 MB
  bf16_t* ctx = (bf16_t*)(ws + 52 * MB);    // 8 MB

  const int nx  = in_sizes[0];
  const int nWq = in_sizes[1];
  const int nWk = in_sizes[2];
  const int nWv = in_sizes[3];
  const int nWo = in_sizes[4];
  hipLaunchKernelGGL(cvt_kernel, dim3((nx  + 4095) / 4096), dim3(256), 0, stream, xf,  xc,  nx);
  hipLaunchKernelGGL(cvt_kernel, dim3((nWq + 4095) / 4096), dim3(256), 0, stream, Wqf, Wqc, nWq);
  hipLaunchKernelGGL(cvt_kernel, dim3((nWk + 4095) / 4096), dim3(256), 0, stream, Wkf, Wkc, nWk);
  hipLaunchKernelGGL(cvt_kernel, dim3((nWv + 4095) / 4096), dim3(256), 0, stream, Wvf, Wvc, nWv);
  hipLaunchKernelGGL(cvt_kernel, dim3((nWo + 4095) / 4096), dim3(256), 0, stream, Wof, Woc, nWo);

  hipLaunchKernelGGL(gemm_qkv_kernel, dim3(16, 32), dim3(256), 0, stream,
                     xc, Wqc, Wkc, Wvc, qb, kb, vb);
  hipLaunchKernelGGL(rope_kernel, dim3(12288), dim3(256), 0, stream, qb, kb, cosT, sinT);
  hipLaunchKernelGGL(vtrans_kernel, dim3(32, 2, 8), dim3(256), 0, stream, vb, vtb);
  hipLaunchKernelGGL(attn_kernel, dim3(16, 16), dim3(256), 0, stream,
                     qb, kb, vtb, ctx);
  hipLaunchKernelGGL(gemm_out_kernel, dim3(16, 16), dim3(256), 0, stream,
                     ctx, Woc, out);
}

// Round 5
// 311.148 us; speedup vs baseline: 1.2956x; 1.2956x over previous
//
#include <hip/hip_runtime.h>
#include <hip/hip_bf16.h>

#define S_LEN 2048
#define HIDN  2048
#define NH    16
#define NKV   8
#define DH    128

typedef __bf16 bf16_t;
typedef __bf16 bf16x8 __attribute__((ext_vector_type(8)));
typedef float  floatx4 __attribute__((ext_vector_type(4)));

#define NEG_BIG (-1.0e30f)

#define BM 128
#define BN 128
#define BK 64

// async global->LDS, 16B per lane. LDS dest must be wave-uniform base + lane*16.
__device__ __forceinline__ void g2l16(const bf16_t* g, bf16_t* l) {
  __builtin_amdgcn_global_load_lds(
      (const __attribute__((address_space(1))) unsigned int*)g,
      (__attribute__((address_space(3))) unsigned int*)l, 16, 0, 0);
}

// barrier that drains LDS ops only (keeps global_load_lds prefetch in flight)
__device__ __forceinline__ void lgkm_barrier() {
  asm volatile("s_waitcnt lgkmcnt(0)\ns_barrier" ::: "memory");
}

// ---------------- f32 -> bf16 input conversion ----------------
__global__ void cvt_kernel(const float* __restrict__ src, bf16_t* __restrict__ dst, int n)
{
  const int base = blockIdx.x * 4096 + threadIdx.x;
  #pragma unroll
  for (int i = 0; i < 16; ++i) {
    int idx = base + i * 256;
    if (idx < n) dst[idx] = (bf16_t)src[idx];
  }
}

// ---------------- GEMM tile (m97: global_load_lds staging + XOR swizzle) ------
// C[m0+..][n0+..] = A[M,K] * Bt[N,K]^T, row-major, row stride K.
// LDS tile [128][64] swizzled: 16B chunk (row,c) stored at physical c ^ (row&7).
__device__ __forceinline__ void gemm_tile(
    const bf16_t* __restrict__ A, const bf16_t* __restrict__ Bt,
    int K, int m0, int n0, floatx4 acc[4][4], bf16_t* As, bf16_t* Bs)
{
  const int tid  = threadIdx.x;
  const int lane = tid & 63;
  const int wave = tid >> 6;
  const int wm = (wave & 1) << 6;
  const int wn = (wave >> 1) << 6;
  const int lr = lane & 15;
  const int lq = lane >> 4;

  #pragma unroll
  for (int i = 0; i < 4; ++i)
    #pragma unroll
    for (int j = 0; j < 4; ++j)
      acc[i][j] = floatx4{0.f, 0.f, 0.f, 0.f};

  for (int k0 = 0; k0 < K; k0 += BK) {
    #pragma unroll
    for (int it = 0; it < 4; ++it) {
      int linear = it * 256 + tid;          // 0..1023
      int row = linear >> 3;                // 128 rows
      int pc  = linear & 7;                 // physical chunk
      int c   = pc ^ (row & 7);             // logical chunk (swizzle)
      g2l16(A  + (size_t)(m0 + row) * K + k0 + c * 8, As + linear * 8);
      g2l16(Bt + (size_t)(n0 + row) * K + k0 + c * 8, Bs + linear * 8);
    }
    __syncthreads();                         // staging landed (vmcnt drain)
    #pragma unroll
    for (int kk = 0; kk < BK; kk += 32) {
      bf16x8 af[4], bfr[4];
      #pragma unroll
      for (int t = 0; t < 4; ++t) {
        int pcr = ((kk >> 3) + lq) ^ (lr & 7);
        af[t]  = *(const bf16x8*)(As + (wm + t * 16 + lr) * BK + pcr * 8);
        bfr[t] = *(const bf16x8*)(Bs + (wn + t * 16 + lr) * BK + pcr * 8);
      }
      #pragma unroll
      for (int i = 0; i < 4; ++i)
        #pragma unroll
        for (int j = 0; j < 4; ++j)
          acc[i][j] = __builtin_amdgcn_mfma_f32_16x16x32_bf16(af[i], bfr[j], acc[i][j], 0, 0, 0);
    }
    __syncthreads();                         // compute done before restage
  }
}

__global__ void __launch_bounds__(256, 2) gemm_qkv_kernel(
    const bf16_t* __restrict__ x, const bf16_t* __restrict__ Wq,
    const bf16_t* __restrict__ Wk, const bf16_t* __restrict__ Wv,
    bf16_t* __restrict__ qb, bf16_t* __restrict__ kb, bf16_t* __restrict__ vb)
{
  __shared__ __align__(16) bf16_t As[BM * BK];
  __shared__ __align__(16) bf16_t Bs[BN * BK];
  const int m0 = blockIdx.x * BM;
  const int nt = blockIdx.y;                 // 0..31 over combined N=4096
  const bf16_t* Bt;
  bf16_t* outp;
  int hbase;
  if (nt < 16)      { Bt = Wq + (size_t)nt * 128 * HIDN;        outp = qb; hbase = nt; }
  else if (nt < 24) { Bt = Wk + (size_t)(nt - 16) * 128 * HIDN; outp = kb; hbase = nt - 16; }
  else              { Bt = Wv + (size_t)(nt - 24) * 128 * HIDN; outp = vb; hbase = nt - 24; }

  floatx4 acc[4][4];
  gemm_tile(x, Bt, HIDN, m0, 0, acc, As, Bs);

  const int lane = threadIdx.x & 63, wave = threadIdx.x >> 6;
  const int wm = (wave & 1) << 6, wn = (wave >> 1) << 6;
  const int lr = lane & 15, lq = lane >> 4;
  #pragma unroll
  for (int i = 0; i < 4; ++i)
    #pragma unroll
    for (int j = 0; j < 4; ++j)
      #pragma unroll
      for (int r = 0; r < 4; ++r) {
        int srow = m0 + wm + i * 16 + lq * 4 + r;
        int d    = wn + j * 16 + lr;          // tile spans exactly one head
        outp[((size_t)hbase * S_LEN + srow) * DH + d] = (bf16_t)acc[i][j][r];
      }
}

// out = ctx[2048,2048] * Wo^T -> d_out (float32)
__global__ void __launch_bounds__(256, 2) gemm_out_kernel(
    const bf16_t* __restrict__ ctx, const bf16_t* __restrict__ Wo,
    float* __restrict__ out)
{
  __shared__ __align__(16) bf16_t As[BM * BK];
  __shared__ __align__(16) bf16_t Bs[BN * BK];
  const int m0 = blockIdx.x * BM;
  const int n0 = blockIdx.y * BN;
  floatx4 acc[4][4];
  gemm_tile(ctx, Wo, HIDN, m0, n0, acc, As, Bs);

  const int lane = threadIdx.x & 63, wave = threadIdx.x >> 6;
  const int wm = (wave & 1) << 6, wn = (wave >> 1) << 6;
  const int lr = lane & 15, lq = lane >> 4;
  #pragma unroll
  for (int i = 0; i < 4; ++i)
    #pragma unroll
    for (int j = 0; j < 4; ++j)
      #pragma unroll
      for (int r = 0; r < 4; ++r) {
        int srow = m0 + wm + i * 16 + lq * 4 + r;
        int col  = n0 + wn + j * 16 + lr;
        out[(size_t)srow * HIDN + col] = acc[i][j][r];
      }
}

// In-place rotate-half RoPE on q and k using the provided f32 tables.
__global__ void rope_kernel(bf16_t* __restrict__ qb, bf16_t* __restrict__ kb,
                            const float* __restrict__ cosT, const float* __restrict__ sinT)
{
  const int NQ = NH * S_LEN * 64;            // 2^21
  const int NK = NKV * S_LEN * 64;           // 2^20
  int idx = blockIdx.x * 256 + threadIdx.x;
  if (idx >= NQ + NK) return;
  bf16_t* base = qb;
  int rem = idx;
  if (idx >= NQ) { base = kb; rem = idx - NQ; }
  int d  = rem & 63;
  int s  = (rem >> 6) & (S_LEN - 1);
  int hh = rem >> 17;
  size_t off = ((size_t)hh * S_LEN + s) * DH;
  float c  = cosT[s * DH + d];
  float sn = sinT[s * DH + d];
  float a = (float)base[off + d];
  float b = (float)base[off + d + 64];
  base[off + d]      = (bf16_t)(a * c - b * sn);
  base[off + d + 64] = (bf16_t)(b * c + a * sn);
}

// v[hkv][s][d] -> vt[hkv][d][s]
__global__ void vtrans_kernel(const bf16_t* __restrict__ vb, bf16_t* __restrict__ vtb)
{
  __shared__ bf16_t tile[64][65];
  const int hkv = blockIdx.z;
  const int s0 = blockIdx.x * 64;
  const int d0 = blockIdx.y * 64;
  const int r = threadIdx.x >> 2;
  const int c = (threadIdx.x & 3) * 16;
  const bf16_t* src = vb + (size_t)hkv * S_LEN * DH;
  #pragma unroll
  for (int u = 0; u < 16; ++u)
    tile[r][c + u] = src[(size_t)(s0 + r) * DH + d0 + c + u];
  __syncthreads();
  bf16_t* dst = vtb + (size_t)hkv * DH * S_LEN;
  #pragma unroll
  for (int u = 0; u < 16; ++u)
    dst[(size_t)(d0 + r) * S_LEN + s0 + c + u] = tile[c + u][r];
}

// Flash attention v2: 256 blocks, each does two complementary 64-row q-tiles
// (qt = w, then 31-w) sequentially -> uniform 17-chunk cost per block.
// Q in registers; K/V double-buffered LDS with global_load_lds prefetch;
// XOR-swizzled LDS (chunk c ^ (row&15)) for conflict-free ds_read_b128.
__global__ void __launch_bounds__(256, 1) attn_kernel(
    const bf16_t* __restrict__ qb, const bf16_t* __restrict__ kb,
    const bf16_t* __restrict__ vtb, bf16_t* __restrict__ ctx)
{
  __shared__ __align__(16) bf16_t Kb[2][128 * 128];  // 64 KB  [kv][d] swizzled
  __shared__ __align__(16) bf16_t Vb[2][128 * 128];  // 64 KB  [d][kv] swizzled
  __shared__ __align__(16) bf16_t Pb[64 * 128];      // 16 KB  [qrow][kv] swizzled
  __shared__ float mpart[2][64];
  __shared__ float lpart[2][64];
  __shared__ float Mrow[64];
  __shared__ float Lrow[64];

  const int tid  = threadIdx.x;
  const int lane = tid & 63, wave = tid >> 6;
  const int wm = (wave & 1) << 5;            // 0 / 32 (row group)
  const int wn = (wave >> 1) << 6;           // 0 / 64 (col group)
  const int lr = lane & 15, lq = lane >> 4;
  const int wnidx = wave >> 1;

  const int h   = blockIdx.x >> 4;
  const int w   = blockIdx.x & 15;
  const int hkv = h >> 1;                    // GQA repeat = 2

  const bf16_t* kbase  = kb  + (size_t)hkv * S_LEN * DH;
  const bf16_t* vtbase = vtb + (size_t)hkv * DH * S_LEN;
  const float scale = 0.08838834764831845f;  // 1/sqrt(128)

  for (int tt = 0; tt < 2; ++tt) {
    const int qt  = tt ? (31 - w) : w;
    const int q0  = qt * 64;
    const int nch = (qt >> 1) + 1;           // chunks of 128 kv

    // Q fragments straight from global (one-time; L2-resident)
    const bf16_t* qbase = qb + ((size_t)h * S_LEN + q0) * DH;
    bf16x8 qf[2][4];
    #pragma unroll
    for (int i = 0; i < 2; ++i)
      #pragma unroll
      for (int kk = 0; kk < 4; ++kk)
        qf[i][kk] = *(const bf16x8*)(qbase + (size_t)(wm + i * 16 + lr) * DH + kk * 32 + lq * 8);

    if (tid < 64) { Mrow[tid] = NEG_BIG; Lrow[tid] = 0.f; }

    floatx4 o[2][4];
    #pragma unroll
    for (int i = 0; i < 2; ++i)
      #pragma unroll
      for (int j = 0; j < 4; ++j)
        o[i][j] = floatx4{0.f, 0.f, 0.f, 0.f};

    auto stage = [&](int cc, int buf) {
      const int kv0 = cc * 128;
      #pragma unroll
      for (int it = 0; it < 8; ++it) {
        int linear = it * 256 + tid;         // 0..2047
        int row = linear >> 4;
        int pc  = linear & 15;
        int c   = pc ^ (row & 15);           // logical chunk (swizzle)
        g2l16(kbase  + (size_t)(kv0 + row) * DH + c * 8,    &Kb[buf][linear * 8]);
        g2l16(vtbase + (size_t)row * S_LEN + kv0 + c * 8,   &Vb[buf][linear * 8]);
      }
    };
    stage(0, 0);

    for (int cc = 0; cc < nch; ++cc) {
      const int buf = cc & 1;
      __syncthreads();                       // staging cc landed; buf^1 free
      if (cc + 1 < nch) stage(cc + 1, buf ^ 1);   // prefetch overlaps body

      const int kv0 = cc * 128;

      // S = Q * K^T
      floatx4 sacc[2][4];
      #pragma unroll
      for (int i = 0; i < 2; ++i)
        #pragma unroll
        for (int j = 0; j < 4; ++j)
          sacc[i][j] = floatx4{0.f, 0.f, 0.f, 0.f};
      #pragma unroll
      for (int kk = 0; kk < 4; ++kk) {
        const int pcr = ((kk << 2) + lq) ^ lr;
        bf16x8 bfr[4];
        #pragma unroll
        for (int t = 0; t < 4; ++t)
          bfr[t] = *(const bf16x8*)(&Kb[buf][(wn + t * 16 + lr) * 128 + pcr * 8]);
        #pragma unroll
        for (int i = 0; i < 2; ++i)
          #pragma unroll
          for (int j = 0; j < 4; ++j)
            sacc[i][j] = __builtin_amdgcn_mfma_f32_16x16x32_bf16(qf[i][kk], bfr[j], sacc[i][j], 0, 0, 0);
      }

      // scale (+ causal mask only on the diagonal chunk)
      if (cc == nch - 1) {
        #pragma unroll
        for (int i = 0; i < 2; ++i)
          #pragma unroll
          for (int j = 0; j < 4; ++j)
            #pragma unroll
            for (int r = 0; r < 4; ++r) {
              int rowg = q0 + wm + i * 16 + lq * 4 + r;
              int colg = kv0 + wn + j * 16 + lr;
              float v = sacc[i][j][r] * scale;
              sacc[i][j][r] = (colg <= rowg) ? v : NEG_BIG;
            }
      } else {
        #pragma unroll
        for (int i = 0; i < 2; ++i)
          #pragma unroll
          for (int j = 0; j < 4; ++j)
            #pragma unroll
            for (int r = 0; r < 4; ++r)
              sacc[i][j][r] *= scale;
      }

      // per-wave row max over its 64-col slice
      float rmax[2][4];
      #pragma unroll
      for (int i = 0; i < 2; ++i)
        #pragma unroll
        for (int r = 0; r < 4; ++r) {
          float v = fmaxf(fmaxf(sacc[i][0][r], sacc[i][1][r]),
                          fmaxf(sacc[i][2][r], sacc[i][3][r]));
          #pragma unroll
          for (int md = 1; md < 16; md <<= 1) v = fmaxf(v, __shfl_xor(v, md, 64));
          rmax[i][r] = v;
        }
      if (lr == 0) {
        #pragma unroll
        for (int i = 0; i < 2; ++i)
          #pragma unroll
          for (int r = 0; r < 4; ++r)
            mpart[wnidx][wm + i * 16 + lq * 4 + r] = rmax[i][r];
      }
      lgkm_barrier();                        // mpart visible (LDS only)

      float mnew[2][4], alphav[2][4], lsum[2][4];
      #pragma unroll
      for (int i = 0; i < 2; ++i)
        #pragma unroll
        for (int r = 0; r < 4; ++r) {
          int row = wm + i * 16 + lq * 4 + r;
          float mc = fmaxf(mpart[0][row], mpart[1][row]);
          float mo = Mrow[row];
          float mn = fmaxf(mo, mc);
          mnew[i][r] = mn;
          alphav[i][r] = __expf(mo - mn);
          lsum[i][r] = 0.f;
        }
      #pragma unroll
      for (int i = 0; i < 2; ++i)
        #pragma unroll
        for (int j = 0; j < 4; ++j) {
          const int cbase = (wn + j * 16) >> 3;
          #pragma unroll
          for (int r = 0; r < 4; ++r) {
            float p = __expf(sacc[i][j][r] - mnew[i][r]);
            lsum[i][r] += p;
            int prow = wm + i * 16 + lq * 4 + r;
            int pcP  = (cbase + (lr >> 3)) ^ (prow & 15);
            Pb[prow * 128 + pcP * 8 + (lr & 7)] = (bf16_t)p;
          }
        }
      #pragma unroll
      for (int i = 0; i < 2; ++i)
        #pragma unroll
        for (int r = 0; r < 4; ++r) {
          float v = lsum[i][r];
          #pragma unroll
          for (int md = 1; md < 16; md <<= 1) v += __shfl_xor(v, md, 64);
          if (lr == 0) lpart[wnidx][wm + i * 16 + lq * 4 + r] = v;
        }
      lgkm_barrier();                        // P + lpart visible

      if (wnidx == 0 && lr == 0) {
        #pragma unroll
        for (int i = 0; i < 2; ++i)
          #pragma unroll
          for (int r = 0; r < 4; ++r) {
            int row = wm + i * 16 + lq * 4 + r;
            Lrow[row] = Lrow[row] * alphav[i][r] + lpart[0][row] + lpart[1][row];
            Mrow[row] = mnew[i][r];
          }
      }

      // O = O*alpha + P*V
      #pragma unroll
      for (int i = 0; i < 2; ++i)
        #pragma unroll
        for (int j = 0; j < 4; ++j)
          #pragma unroll
          for (int r = 0; r < 4; ++r)
            o[i][j][r] *= alphav[i][r];
      #pragma unroll
      for (int kk = 0; kk < 4; ++kk) {
        const int pcr = ((kk << 2) + lq) ^ lr;
        bf16x8 paf[2], vbf[4];
        #pragma unroll
        for (int i = 0; i < 2; ++i)
          paf[i] = *(const bf16x8*)(&Pb[(wm + i * 16 + lr) * 128 + pcr * 8]);
        #pragma unroll
        for (int t = 0; t < 4; ++t)
          vbf[t] = *(const bf16x8*)(&Vb[buf][(wn + t * 16 + lr) * 128 + pcr * 8]);
        #pragma unroll
        for (int i = 0; i < 2; ++i)
          #pragma unroll
          for (int j = 0; j < 4; ++j)
            o[i][j] = __builtin_amdgcn_mfma_f32_16x16x32_bf16(paf[i], vbf[j], o[i][j], 0, 0, 0);
      }
    }

    __syncthreads();                         // Lrow final; all LDS reads done
    float inv[2][4];
    #pragma unroll
    for (int i = 0; i < 2; ++i)
      #pragma unroll
      for (int r = 0; r < 4; ++r)
        inv[i][r] = 1.0f / Lrow[wm + i * 16 + lq * 4 + r];
    lgkm_barrier();                          // Lrow reads done before re-init
    #pragma unroll
    for (int i = 0; i < 2; ++i)
      #pragma unroll
      for (int j = 0; j < 4; ++j)
        #pragma unroll
        for (int r = 0; r < 4; ++r) {
          int srow = q0 + wm + i * 16 + lq * 4 + r;
          int col  = h * DH + wn + j * 16 + lr;
          ctx[(size_t)srow * HIDN + col] = (bf16_t)(o[i][j][r] * inv[i][r]);
        }
  }
}

extern "C" void kernel_launch(void* const* d_in, const int* in_sizes, int n_in,
                              void* d_out, int out_size, void* d_ws, size_t ws_size,
                              hipStream_t stream)
{
  const float* xf   = (const float*)d_in[0];
  const float* Wqf  = (const float*)d_in[1];
  const float* Wkf  = (const float*)d_in[2];
  const float* Wvf  = (const float*)d_in[3];
  const float* Wof  = (const float*)d_in[4];
  const float* cosT = (const float*)d_in[5];
  const float* sinT = (const float*)d_in[6];
  float* out = (float*)d_out;

  char* ws = (char*)d_ws;
  const size_t MB = 1u << 20;
  bf16_t* xc  = (bf16_t*)(ws);              // 8 MB
  bf16_t* Wqc = (bf16_t*)(ws + 8  * MB);    // 8 MB
  bf16_t* Wkc = (bf16_t*)(ws + 16 * MB);    // 4 MB
  bf16_t* Wvc = (bf16_t*)(ws + 20 * MB);    // 4 MB
  bf16_t* Woc = (bf16_t*)(ws + 24 * MB);    // 8 MB
  bf16_t* qb  = (bf16_t*)(ws + 32 * MB);    // 8 MB
  bf16_t* kb  = (bf16_t*)(ws + 40 * MB);    // 4 MB
  bf16_t* vb  = (bf16_t*)(ws + 44 * MB);    // 4 MB
  bf16_t* vtb = (bf16_t*)(ws + 48 * MB);    // 4 MB
  bf16_t* ctx = (bf16_t*)(ws + 52 * MB);    // 8 MB

  const int nx  = in_sizes[0];
  const int nWq = in_sizes[1];
  const int nWk = in_sizes[2];
  const int nWv = in_sizes[3];
  const int nWo = in_sizes[4];
  hipLaunchKernelGGL(cvt_kernel, dim3((nx  + 4095) / 4096), dim3(256), 0, stream, xf,  xc,  nx);
  hipLaunchKernelGGL(cvt_kernel, dim3((nWq + 4095) / 4096), dim3(256), 0, stream, Wqf, Wqc, nWq);
  hipLaunchKernelGGL(cvt_kernel, dim3((nWk + 4095) / 4096), dim3(256), 0, stream, Wkf, Wkc, nWk);
  hipLaunchKernelGGL(cvt_kernel, dim3((nWv + 4095) / 4096), dim3(256), 0, stream, Wvf, Wvc, nWv);
  hipLaunchKernelGGL(cvt_kernel, dim3((nWo + 4095) / 4096), dim3(256), 0, stream, Wof, Woc, nWo);

  hipLaunchKernelGGL(gemm_qkv_kernel, dim3(16, 32), dim3(256), 0, stream,
                     xc, Wqc, Wkc, Wvc, qb, kb, vb);
  hipLaunchKernelGGL(rope_kernel, dim3(12288), dim3(256), 0, stream, qb, kb, cosT, sinT);
  hipLaunchKernelGGL(vtrans_kernel, dim3(32, 2, 8), dim3(256), 0, stream, vb, vtb);
  hipLaunchKernelGGL(attn_kernel, dim3(256), dim3(256), 0, stream,
                     qb, kb, vtb, ctx);
  hipLaunchKernelGGL(gemm_out_kernel, dim3(16, 16), dim3(256), 0, stream,
                     ctx, Woc, out);
}

// Round 6
// 251.750 us; speedup vs baseline: 1.6013x; 1.2359x over previous
//
#include <hip/hip_runtime.h>
#include <hip/hip_bf16.h>

#define S_LEN 2048
#define HIDN  2048
#define NH    16
#define NKV   8
#define DH    128

typedef __bf16 bf16_t;
typedef __bf16 bf16x4 __attribute__((ext_vector_type(4)));
typedef __bf16 bf16x8 __attribute__((ext_vector_type(8)));
typedef float  floatx4 __attribute__((ext_vector_type(4)));

#define NEG_BIG (-1.0e30f)

#define BM 128
#define BN 128
#define BK 64

// async global->LDS, 16B per lane. LDS dest must be wave-uniform base + lane*16.
__device__ __forceinline__ void g2l16(const bf16_t* g, bf16_t* l) {
  __builtin_amdgcn_global_load_lds(
      (const __attribute__((address_space(1))) unsigned int*)g,
      (__attribute__((address_space(3))) unsigned int*)l, 16, 0, 0);
}

// ---------------- fused f32 -> bf16 conversion for all 5 inputs ----------------
// segments (4096-elem blocks): x 1024 | Wq 1024 | Wk 512 | Wv 512 | Wo 1024
__global__ void cvt_all_kernel(const float* __restrict__ x,  const float* __restrict__ wq,
                               const float* __restrict__ wk, const float* __restrict__ wv,
                               const float* __restrict__ wo,
                               bf16_t* __restrict__ xc,  bf16_t* __restrict__ wqc,
                               bf16_t* __restrict__ wkc, bf16_t* __restrict__ wvc,
                               bf16_t* __restrict__ woc)
{
  const int b = blockIdx.x;
  const float* src; bf16_t* dst; int off;
  if      (b < 1024) { src = x;  dst = xc;  off = b; }
  else if (b < 2048) { src = wq; dst = wqc; off = b - 1024; }
  else if (b < 2560) { src = wk; dst = wkc; off = b - 2048; }
  else if (b < 3072) { src = wv; dst = wvc; off = b - 2560; }
  else               { src = wo; dst = woc; off = b - 3072; }
  const int base = off * 4096 + threadIdx.x;
  #pragma unroll
  for (int i = 0; i < 16; ++i)
    dst[base + i * 256] = (bf16_t)src[base + i * 256];
}

// ---------------- GEMM tile (m97: global_load_lds staging + XOR swizzle) ------
__device__ __forceinline__ void gemm_tile(
    const bf16_t* __restrict__ A, const bf16_t* __restrict__ Bt,
    int K, int m0, int n0, floatx4 acc[4][4], bf16_t* As, bf16_t* Bs)
{
  const int tid  = threadIdx.x;
  const int lane = tid & 63;
  const int wave = tid >> 6;
  const int wm = (wave & 1) << 6;
  const int wn = (wave >> 1) << 6;
  const int lr = lane & 15;
  const int lq = lane >> 4;

  #pragma unroll
  for (int i = 0; i < 4; ++i)
    #pragma unroll
    for (int j = 0; j < 4; ++j)
      acc[i][j] = floatx4{0.f, 0.f, 0.f, 0.f};

  for (int k0 = 0; k0 < K; k0 += BK) {
    #pragma unroll
    for (int it = 0; it < 4; ++it) {
      int linear = it * 256 + tid;
      int row = linear >> 3;
      int pc  = linear & 7;
      int c   = pc ^ (row & 7);
      g2l16(A  + (size_t)(m0 + row) * K + k0 + c * 8, As + linear * 8);
      g2l16(Bt + (size_t)(n0 + row) * K + k0 + c * 8, Bs + linear * 8);
    }
    __syncthreads();
    #pragma unroll
    for (int kk = 0; kk < BK; kk += 32) {
      bf16x8 af[4], bfr[4];
      #pragma unroll
      for (int t = 0; t < 4; ++t) {
        int pcr = ((kk >> 3) + lq) ^ (lr & 7);
        af[t]  = *(const bf16x8*)(As + (wm + t * 16 + lr) * BK + pcr * 8);
        bfr[t] = *(const bf16x8*)(Bs + (wn + t * 16 + lr) * BK + pcr * 8);
      }
      #pragma unroll
      for (int i = 0; i < 4; ++i)
        #pragma unroll
        for (int j = 0; j < 4; ++j)
          acc[i][j] = __builtin_amdgcn_mfma_f32_16x16x32_bf16(af[i], bfr[j], acc[i][j], 0, 0, 0);
    }
    __syncthreads();
  }
}

__global__ void __launch_bounds__(256, 2) gemm_qkv_kernel(
    const bf16_t* __restrict__ x, const bf16_t* __restrict__ Wq,
    const bf16_t* __restrict__ Wk, const bf16_t* __restrict__ Wv,
    bf16_t* __restrict__ qb, bf16_t* __restrict__ kb, bf16_t* __restrict__ vb)
{
  __shared__ __align__(16) bf16_t As[BM * BK];
  __shared__ __align__(16) bf16_t Bs[BN * BK];
  const int m0 = blockIdx.x * BM;
  const int nt = blockIdx.y;
  const bf16_t* Bt;
  bf16_t* outp;
  int hbase;
  if (nt < 16)      { Bt = Wq + (size_t)nt * 128 * HIDN;        outp = qb; hbase = nt; }
  else if (nt < 24) { Bt = Wk + (size_t)(nt - 16) * 128 * HIDN; outp = kb; hbase = nt - 16; }
  else              { Bt = Wv + (size_t)(nt - 24) * 128 * HIDN; outp = vb; hbase = nt - 24; }

  floatx4 acc[4][4];
  gemm_tile(x, Bt, HIDN, m0, 0, acc, As, Bs);

  const int lane = threadIdx.x & 63, wave = threadIdx.x >> 6;
  const int wm = (wave & 1) << 6, wn = (wave >> 1) << 6;
  const int lr = lane & 15, lq = lane >> 4;
  #pragma unroll
  for (int i = 0; i < 4; ++i)
    #pragma unroll
    for (int j = 0; j < 4; ++j)
      #pragma unroll
      for (int r = 0; r < 4; ++r) {
        int srow = m0 + wm + i * 16 + lq * 4 + r;
        int d    = wn + j * 16 + lr;
        outp[((size_t)hbase * S_LEN + srow) * DH + d] = (bf16_t)acc[i][j][r];
      }
}

__global__ void __launch_bounds__(256, 2) gemm_out_kernel(
    const bf16_t* __restrict__ ctx, const bf16_t* __restrict__ Wo,
    float* __restrict__ out)
{
  __shared__ __align__(16) bf16_t As[BM * BK];
  __shared__ __align__(16) bf16_t Bs[BN * BK];
  const int m0 = blockIdx.x * BM;
  const int n0 = blockIdx.y * BN;
  floatx4 acc[4][4];
  gemm_tile(ctx, Wo, HIDN, m0, n0, acc, As, Bs);

  const int lane = threadIdx.x & 63, wave = threadIdx.x >> 6;
  const int wm = (wave & 1) << 6, wn = (wave >> 1) << 6;
  const int lr = lane & 15, lq = lane >> 4;
  #pragma unroll
  for (int i = 0; i < 4; ++i)
    #pragma unroll
    for (int j = 0; j < 4; ++j)
      #pragma unroll
      for (int r = 0; r < 4; ++r) {
        int srow = m0 + wm + i * 16 + lq * 4 + r;
        int col  = n0 + wn + j * 16 + lr;
        out[(size_t)srow * HIDN + col] = acc[i][j][r];
      }
}

// ---------------- fused RoPE (q,k) + V-transpose ----------------
__global__ void rope_vtrans_kernel(bf16_t* __restrict__ qb, bf16_t* __restrict__ kb,
                                   const float* __restrict__ cosT, const float* __restrict__ sinT,
                                   const bf16_t* __restrict__ vb, bf16_t* __restrict__ vtb)
{
  const int b = blockIdx.x;
  if (b < 12288) {
    // RoPE: idx over NQ + NK half-pairs
    const int NQ = NH * S_LEN * 64;
    int idx = b * 256 + threadIdx.x;
    bf16_t* base = qb;
    int rem = idx;
    if (idx >= NQ) { base = kb; rem = idx - NQ; }
    int d  = rem & 63;
    int s  = (rem >> 6) & (S_LEN - 1);
    int hh = rem >> 17;
    size_t off = ((size_t)hh * S_LEN + s) * DH;
    float c  = cosT[s * DH + d];
    float sn = sinT[s * DH + d];
    float a  = (float)base[off + d];
    float bb = (float)base[off + d + 64];
    base[off + d]      = (bf16_t)(a * c - bb * sn);
    base[off + d + 64] = (bf16_t)(bb * c + a * sn);
  } else {
    // vtrans: v[hkv][s][d] -> vt[hkv][d][s]
    __shared__ bf16_t tile[64][65];
    const int idx = b - 12288;                 // 0..511
    const int hkv = idx >> 6;
    const int rem = idx & 63;
    const int s0 = (rem >> 1) * 64;
    const int d0 = (rem & 1) * 64;
    const int r = threadIdx.x >> 2;
    const int c = (threadIdx.x & 3) * 16;
    const bf16_t* src = vb + (size_t)hkv * S_LEN * DH;
    #pragma unroll
    for (int u = 0; u < 16; ++u)
      tile[r][c + u] = src[(size_t)(s0 + r) * DH + d0 + c + u];
    __syncthreads();
    bf16_t* dst = vtb + (size_t)hkv * DH * S_LEN;
    #pragma unroll
    for (int u = 0; u < 16; ++u)
      dst[(size_t)(d0 + r) * S_LEN + s0 + c + u] = tile[c + u][r];
  }
}

// ---------------- Flash attention v3: wave-local softmax (S^T form) ----------
// 256 blocks; block (h, w) does q-tiles qt=w and qt=31-w (uniform 17 chunks).
// Each wave owns 16 q-rows. S^T = MFMA(A=K, B=Q): C-layout col = qrow = lane&15
// -> softmax state in registers, reductions = 2 shfl_xor, NO softmax barriers.
// PV as O^T = MFMA(A=V^T, B=P^T); P goes through wave-private LDS scratch.
#define PSTR 144   // P scratch row stride in bf16 (128 + 16 pad)
__global__ void __launch_bounds__(256, 1) attn_kernel(
    const bf16_t* __restrict__ qb, const bf16_t* __restrict__ kb,
    const bf16_t* __restrict__ vtb, bf16_t* __restrict__ ctx)
{
  __shared__ __align__(16) bf16_t Kb[2][128 * 128];   // [kv][d] swizzled
  __shared__ __align__(16) bf16_t Vb[2][128 * 128];   // [d][kv] swizzled
  __shared__ __align__(16) bf16_t Pb[4][16 * PSTR];   // wave-private P [qr][kv]

  const int tid  = threadIdx.x;
  const int lane = tid & 63, wave = tid >> 6;
  const int lr   = lane & 15, quad = lane >> 4;

  const int h   = blockIdx.x >> 4;
  const int w   = blockIdx.x & 15;
  const int hkv = h >> 1;

  const bf16_t* kbase  = kb  + (size_t)hkv * S_LEN * DH;
  const bf16_t* vtbase = vtb + (size_t)hkv * DH * S_LEN;
  const float scale = 0.08838834764831845f;  // 1/sqrt(128)
  bf16_t* pmine = &Pb[wave][0];

  auto stage = [&](int cc, int buf) {
    const int kv0 = cc * 128;
    #pragma unroll
    for (int it = 0; it < 8; ++it) {
      int linear = it * 256 + tid;
      int row = linear >> 4;
      int pc  = linear & 15;
      int c   = pc ^ (row & 15);
      g2l16(kbase  + (size_t)(kv0 + row) * DH + c * 8,  &Kb[buf][linear * 8]);
      g2l16(vtbase + (size_t)row * S_LEN + kv0 + c * 8, &Vb[buf][linear * 8]);
    }
  };

  for (int tt = 0; tt < 2; ++tt) {
    const int qt  = tt ? (31 - w) : w;
    const int q0  = qt * 64;
    const int nch = (qt >> 1) + 1;
    const int qrow_g = q0 + wave * 16 + lr;    // this thread's q-row

    // Q B-fragments (lane holds Q[qrow=lr][d=quad*8+j]) straight from global
    const bf16_t* qrp = qb + ((size_t)h * S_LEN + qrow_g) * DH;
    bf16x8 qf[4];
    #pragma unroll
    for (int kk = 0; kk < 4; ++kk)
      qf[kk] = *(const bf16x8*)(qrp + kk * 32 + quad * 8);

    float m_r = NEG_BIG, l_r = 0.f;
    floatx4 o[8];
    #pragma unroll
    for (int t = 0; t < 8; ++t) o[t] = floatx4{0.f, 0.f, 0.f, 0.f};

    stage(0, 0);

    for (int cc = 0; cc < nch; ++cc) {
      const int buf = cc & 1;
      __syncthreads();                         // staging cc landed; buf^1 free
      if (cc + 1 < nch) stage(cc + 1, buf ^ 1);
      const int kv0 = cc * 128;

      // S^T = K * Q^T : tiles over kv (8 x 16 rows), K-dim = d (4 x 32)
      floatx4 sacc[8];
      #pragma unroll
      for (int t = 0; t < 8; ++t) sacc[t] = floatx4{0.f, 0.f, 0.f, 0.f};
      #pragma unroll
      for (int kk = 0; kk < 4; ++kk) {
        const int pc = ((kk << 2) + quad) ^ lr;
        #pragma unroll
        for (int t = 0; t < 8; ++t) {
          bf16x8 kf = *(const bf16x8*)(&Kb[buf][(t * 16 + lr) * 128 + pc * 8]);
          sacc[t] = __builtin_amdgcn_mfma_f32_16x16x32_bf16(kf, qf[kk], sacc[t], 0, 0, 0);
        }
      }

      // causal mask (diagonal chunk only); raw domain
      if (cc == nch - 1) {
        #pragma unroll
        for (int t = 0; t < 8; ++t)
          #pragma unroll
          for (int r = 0; r < 4; ++r) {
            int kv = kv0 + t * 16 + quad * 4 + r;
            if (kv > qrow_g) sacc[t][r] = NEG_BIG;
          }
      }

      // row max (32 regs + 2 cross-quad shuffles), then scale
      float mx = sacc[0][0];
      #pragma unroll
      for (int t = 0; t < 8; ++t)
        #pragma unroll
        for (int r = 0; r < 4; ++r) mx = fmaxf(mx, sacc[t][r]);
      mx = fmaxf(mx, __shfl_xor(mx, 16, 64));
      mx = fmaxf(mx, __shfl_xor(mx, 32, 64));
      const float mn = fmaxf(m_r, mx * scale);
      const float alpha = __expf(m_r - mn);

      // p = exp(s*scale - mn), pack to bf16, wave-private LDS store, row sum
      float lc = 0.f;
      #pragma unroll
      for (int t = 0; t < 8; ++t) {
        bf16x4 pk;
        #pragma unroll
        for (int r = 0; r < 4; ++r) {
          float p = __expf(fmaf(sacc[t][r], scale, -mn));
          lc += p;
          pk[r] = (bf16_t)p;
        }
        *(bf16x4*)(pmine + lr * PSTR + t * 16 + quad * 4) = pk;
      }
      lc += __shfl_xor(lc, 16, 64);
      lc += __shfl_xor(lc, 32, 64);
      l_r = l_r * alpha + lc;
      m_r = mn;

      // O^T = O^T*alpha + V^T * P^T
      #pragma unroll
      for (int t = 0; t < 8; ++t)
        #pragma unroll
        for (int r = 0; r < 4; ++r) o[t][r] *= alpha;
      #pragma unroll
      for (int ks = 0; ks < 4; ++ks) {
        bf16x8 pf = *(const bf16x8*)(pmine + lr * PSTR + ks * 32 + quad * 8);
        const int pc = ((ks << 2) + quad) ^ lr;
        #pragma unroll
        for (int t = 0; t < 8; ++t) {
          bf16x8 vf = *(const bf16x8*)(&Vb[buf][(t * 16 + lr) * 128 + pc * 8]);
          o[t] = __builtin_amdgcn_mfma_f32_16x16x32_bf16(vf, pf, o[t], 0, 0, 0);
        }
      }
    }

    __syncthreads();                           // all reads of Kb/Vb done before next tile's stage
    const float inv = 1.0f / l_r;
    bf16_t* crow = ctx + (size_t)qrow_g * HIDN + h * DH;
    #pragma unroll
    for (int t = 0; t < 8; ++t) {
      bf16x4 ov;
      #pragma unroll
      for (int r = 0; r < 4; ++r) ov[r] = (bf16_t)(o[t][r] * inv);
      *(bf16x4*)(crow + t * 16 + quad * 4) = ov;
    }
  }
}

extern "C" void kernel_launch(void* const* d_in, const int* in_sizes, int n_in,
                              void* d_out, int out_size, void* d_ws, size_t ws_size,
                              hipStream_t stream)
{
  const float* xf   = (const float*)d_in[0];
  const float* Wqf  = (const float*)d_in[1];
  const float* Wkf  = (const float*)d_in[2];
  const float* Wvf  = (const float*)d_in[3];
  const float* Wof  = (const float*)d_in[4];
  const float* cosT = (const float*)d_in[5];
  const float* sinT = (const float*)d_in[6];
  float* out = (float*)d_out;

  char* ws = (char*)d_ws;
  const size_t MB = 1u << 20;
  bf16_t* xc  = (bf16_t*)(ws);              // 8 MB
  bf16_t* Wqc = (bf16_t*)(ws + 8  * MB);    // 8 MB
  bf16_t* Wkc = (bf16_t*)(ws + 16 * MB);    // 4 MB
  bf16_t* Wvc = (bf16_t*)(ws + 20 * MB);    // 4 MB
  bf16_t* Woc = (bf16_t*)(ws + 24 * MB);    // 8 MB
  bf16_t* qb  = (bf16_t*)(ws + 32 * MB);    // 8 MB
  bf16_t* kb  = (bf16_t*)(ws + 40 * MB);    // 4 MB
  bf16_t* vb  = (bf16_t*)(ws + 44 * MB);    // 4 MB
  bf16_t* vtb = (bf16_t*)(ws + 48 * MB);    // 4 MB
  bf16_t* ctx = (bf16_t*)(ws + 52 * MB);    // 8 MB

  hipLaunchKernelGGL(cvt_all_kernel, dim3(4096), dim3(256), 0, stream,
                     xf, Wqf, Wkf, Wvf, Wof, xc, Wqc, Wkc, Wvc, Woc);
  hipLaunchKernelGGL(gemm_qkv_kernel, dim3(16, 32), dim3(256), 0, stream,
                     xc, Wqc, Wkc, Wvc, qb, kb, vb);
  hipLaunchKernelGGL(rope_vtrans_kernel, dim3(12800), dim3(256), 0, stream,
                     qb, kb, cosT, sinT, vb, vtb);
  hipLaunchKernelGGL(attn_kernel, dim3(256), dim3(256), 0, stream,
                     qb, kb, vtb, ctx);
  hipLaunchKernelGGL(gemm_out_kernel, dim3(16, 16), dim3(256), 0, stream,
                     ctx, Woc, out);
}

// Round 7
// 237.892 us; speedup vs baseline: 1.6946x; 1.0583x over previous
//
#include <hip/hip_runtime.h>
#include <hip/hip_bf16.h>

#define S_LEN 2048
#define HIDN  2048
#define NH    16
#define NKV   8
#define DH    128

typedef __bf16 bf16_t;
typedef __bf16 bf16x4 __attribute__((ext_vector_type(4)));
typedef __bf16 bf16x8 __attribute__((ext_vector_type(8)));
typedef float  floatx4 __attribute__((ext_vector_type(4)));

#define NEG_BIG (-1.0e30f)

#define BM 128
#define BN 128
#define BK 64

// async global->LDS, 16B per lane. LDS dest must be wave-uniform base + lane*16.
__device__ __forceinline__ void g2l16(const bf16_t* g, bf16_t* l) {
  __builtin_amdgcn_global_load_lds(
      (const __attribute__((address_space(1))) unsigned int*)g,
      (__attribute__((address_space(3))) unsigned int*)l, 16, 0, 0);
}

// ---------------- fused f32 -> bf16 conversion for all 5 inputs ----------------
__global__ void cvt_all_kernel(const float* __restrict__ x,  const float* __restrict__ wq,
                               const float* __restrict__ wk, const float* __restrict__ wv,
                               const float* __restrict__ wo,
                               bf16_t* __restrict__ xc,  bf16_t* __restrict__ wqc,
                               bf16_t* __restrict__ wkc, bf16_t* __restrict__ wvc,
                               bf16_t* __restrict__ woc)
{
  const int b = blockIdx.x;
  const float* src; bf16_t* dst; int off;
  if      (b < 1024) { src = x;  dst = xc;  off = b; }
  else if (b < 2048) { src = wq; dst = wqc; off = b - 1024; }
  else if (b < 2560) { src = wk; dst = wkc; off = b - 2048; }
  else if (b < 3072) { src = wv; dst = wvc; off = b - 2560; }
  else               { src = wo; dst = woc; off = b - 3072; }
  const int base = off * 4096 + threadIdx.x;
  #pragma unroll
  for (int i = 0; i < 16; ++i)
    dst[base + i * 256] = (bf16_t)src[base + i * 256];
}

// ---------------- GEMM tile (m97: global_load_lds staging + XOR swizzle) ------
__device__ __forceinline__ void gemm_tile(
    const bf16_t* __restrict__ A, const bf16_t* __restrict__ Bt,
    int K, int m0, int n0, floatx4 acc[4][4], bf16_t* As, bf16_t* Bs)
{
  const int tid  = threadIdx.x;
  const int lane = tid & 63;
  const int wave = tid >> 6;
  const int wm = (wave & 1) << 6;
  const int wn = (wave >> 1) << 6;
  const int lr = lane & 15;
  const int lq = lane >> 4;

  #pragma unroll
  for (int i = 0; i < 4; ++i)
    #pragma unroll
    for (int j = 0; j < 4; ++j)
      acc[i][j] = floatx4{0.f, 0.f, 0.f, 0.f};

  for (int k0 = 0; k0 < K; k0 += BK) {
    #pragma unroll
    for (int it = 0; it < 4; ++it) {
      int linear = it * 256 + tid;
      int row = linear >> 3;
      int pc  = linear & 7;
      int c   = pc ^ (row & 7);
      g2l16(A  + (size_t)(m0 + row) * K + k0 + c * 8, As + linear * 8);
      g2l16(Bt + (size_t)(n0 + row) * K + k0 + c * 8, Bs + linear * 8);
    }
    __syncthreads();
    #pragma unroll
    for (int kk = 0; kk < BK; kk += 32) {
      bf16x8 af[4], bfr[4];
      #pragma unroll
      for (int t = 0; t < 4; ++t) {
        int pcr = ((kk >> 3) + lq) ^ (lr & 7);
        af[t]  = *(const bf16x8*)(As + (wm + t * 16 + lr) * BK + pcr * 8);
        bfr[t] = *(const bf16x8*)(Bs + (wn + t * 16 + lr) * BK + pcr * 8);
      }
      #pragma unroll
      for (int i = 0; i < 4; ++i)
        #pragma unroll
        for (int j = 0; j < 4; ++j)
          acc[i][j] = __builtin_amdgcn_mfma_f32_16x16x32_bf16(af[i], bfr[j], acc[i][j], 0, 0, 0);
    }
    __syncthreads();
  }
}

// QKV GEMM with fused RoPE (q,k heads) and V-transpose (v heads) epilogue.
__global__ void __launch_bounds__(256, 2) gemm_qkv_kernel(
    const bf16_t* __restrict__ x, const bf16_t* __restrict__ Wq,
    const bf16_t* __restrict__ Wk, const bf16_t* __restrict__ Wv,
    bf16_t* __restrict__ qb, bf16_t* __restrict__ kb, bf16_t* __restrict__ vtb,
    const float* __restrict__ cosT, const float* __restrict__ sinT)
{
  __shared__ __align__(16) bf16_t As[BM * BK];
  __shared__ __align__(16) bf16_t Bs[BN * BK];
  __shared__ __align__(16) bf16_t Epi[128 * 132];   // epilogue exchange tile
  const int tid = threadIdx.x;
  const int m0 = blockIdx.x * BM;
  const int nt = blockIdx.y;
  const bf16_t* Bt;
  int hbase;
  if (nt < 16)      { Bt = Wq + (size_t)nt * 128 * HIDN;        hbase = nt; }
  else if (nt < 24) { Bt = Wk + (size_t)(nt - 16) * 128 * HIDN; hbase = nt - 16; }
  else              { Bt = Wv + (size_t)(nt - 24) * 128 * HIDN; hbase = nt - 24; }

  floatx4 acc[4][4];
  gemm_tile(x, Bt, HIDN, m0, 0, acc, As, Bs);

  const int lane = tid & 63, wave = tid >> 6;
  const int wm = (wave & 1) << 6, wn = (wave >> 1) << 6;
  const int lr = lane & 15, lq = lane >> 4;
  #pragma unroll
  for (int i = 0; i < 4; ++i)
    #pragma unroll
    for (int j = 0; j < 4; ++j)
      #pragma unroll
      for (int r = 0; r < 4; ++r) {
        int row = wm + i * 16 + lq * 4 + r;
        int col = wn + j * 16 + lr;
        Epi[row * 132 + col] = (bf16_t)acc[i][j][r];
      }
  __syncthreads();

  if (nt < 24) {
    // RoPE: out[d] = a*cos - b*sin; out[d+64] = b*cos + a*sin  (cos[d+64]==cos[d])
    bf16_t* outp = (nt < 16) ? qb : kb;
    #pragma unroll
    for (int u = 0; u < 32; ++u) {
      int idx = u * 256 + tid;              // 0..8191
      int dd = idx & 63, s = idx >> 6;
      float a = (float)Epi[s * 132 + dd];
      float b = (float)Epi[s * 132 + dd + 64];
      int sg = m0 + s;
      float cv = cosT[sg * DH + dd];
      float sv = sinT[sg * DH + dd];
      size_t off = ((size_t)hbase * S_LEN + sg) * DH;
      outp[off + dd]      = (bf16_t)(a * cv - b * sv);
      outp[off + dd + 64] = (bf16_t)(b * cv + a * sv);
    }
  } else {
    // V transpose: vt[hkv][d][s]
    bf16_t* dst = vtb + (size_t)hbase * DH * S_LEN;
    #pragma unroll
    for (int u = 0; u < 64; ++u) {
      int idx = u * 256 + tid;              // 0..16383
      int sl = idx & 127, d = idx >> 7;
      dst[(size_t)d * S_LEN + m0 + sl] = Epi[sl * 132 + d];
    }
  }
}

__global__ void __launch_bounds__(256, 2) gemm_out_kernel(
    const bf16_t* __restrict__ ctx, const bf16_t* __restrict__ Wo,
    float* __restrict__ out)
{
  __shared__ __align__(16) bf16_t As[BM * BK];
  __shared__ __align__(16) bf16_t Bs[BN * BK];
  const int m0 = blockIdx.x * BM;
  const int n0 = blockIdx.y * BN;
  floatx4 acc[4][4];
  gemm_tile(ctx, Wo, HIDN, m0, n0, acc, As, Bs);

  const int lane = threadIdx.x & 63, wave = threadIdx.x >> 6;
  const int wm = (wave & 1) << 6, wn = (wave >> 1) << 6;
  const int lr = lane & 15, lq = lane >> 4;
  #pragma unroll
  for (int i = 0; i < 4; ++i)
    #pragma unroll
    for (int j = 0; j < 4; ++j)
      #pragma unroll
      for (int r = 0; r < 4; ++r) {
        int srow = m0 + wm + i * 16 + lq * 4 + r;
        int col  = n0 + wn + j * 16 + lr;
        out[(size_t)srow * HIDN + col] = acc[i][j][r];
      }
}

// ---------------- Flash attention v4: 2 blocks/CU, kv-chunk 64 ----------------
// 512 blocks, one 64-row q-tile each. Complement mapping: blocks b and b+256
// have qt summing to 31 (balanced if CU = b%256 round-robin; otherwise 2-deep
// co-residency still hides staging-barrier stalls).
// Wave-local softmax via S^T = MFMA(A=K, B=Q) (qrow = lane&15, state in regs).
// PV: O^T = MFMA(A=V^T, B=P^T); P in wave-private swizzled LDS.
__global__ void __launch_bounds__(256, 2) attn_kernel(
    const bf16_t* __restrict__ qb, const bf16_t* __restrict__ kb,
    const bf16_t* __restrict__ vtb, bf16_t* __restrict__ ctx)
{
  __shared__ __align__(16) bf16_t Kb[2][64 * 128];   // [kv][d] swizzled, 16 KB each
  __shared__ __align__(16) bf16_t Vb[2][128 * 64];   // [d][kv] swizzled, 16 KB each
  __shared__ __align__(16) bf16_t Pb[4][16 * 64];    // wave-private P, swizzled

  const int tid  = threadIdx.x;
  const int lane = tid & 63, wave = tid >> 6;
  const int lr   = lane & 15, quad = lane >> 4;

  const int b = blockIdx.x;
  int h, qt;
  if (b < 256) { h = b >> 5;              qt = b & 31; }
  else         { int c = b - 256; h = 8 + (c >> 5); qt = 31 - (c & 31); }
  const int hkv = h >> 1;
  const int q0  = qt * 64;
  const int nch = qt + 1;                  // chunks of 64 kv
  const int qrow_g = q0 + wave * 16 + lr;  // this thread's q-row

  const bf16_t* kbase  = kb  + (size_t)hkv * S_LEN * DH;
  const bf16_t* vtbase = vtb + (size_t)hkv * DH * S_LEN;
  const float scale = 0.08838834764831845f;  // 1/sqrt(128)
  bf16_t* pmine = &Pb[wave][0];

  // Q B-fragments (lane holds Q[qrow=lr][d=quad*8+j]) straight from global
  const bf16_t* qrp = qb + ((size_t)h * S_LEN + qrow_g) * DH;
  bf16x8 qf[4];
  #pragma unroll
  for (int kk = 0; kk < 4; ++kk)
    qf[kk] = *(const bf16x8*)(qrp + kk * 32 + quad * 8);

  auto stage = [&](int cc, int buf) {
    const int kv0 = cc * 64;
    #pragma unroll
    for (int it = 0; it < 4; ++it) {
      int linear = it * 256 + tid;           // 0..1023
      int krow = linear >> 4, kpc = linear & 15;
      int kc = kpc ^ (krow & 15);
      g2l16(kbase + (size_t)(kv0 + krow) * DH + kc * 8, &Kb[buf][linear * 8]);
      int vrow = linear >> 3, vpc = linear & 7;
      int vc = vpc ^ (vrow & 7);
      g2l16(vtbase + (size_t)vrow * S_LEN + kv0 + vc * 8, &Vb[buf][linear * 8]);
    }
  };

  float m_r = NEG_BIG, l_r = 0.f;
  floatx4 o[8];
  #pragma unroll
  for (int t = 0; t < 8; ++t) o[t] = floatx4{0.f, 0.f, 0.f, 0.f};

  stage(0, 0);

  for (int cc = 0; cc < nch; ++cc) {
    const int buf = cc & 1;
    __syncthreads();                         // staging cc landed; buf^1 free
    if (cc + 1 < nch) stage(cc + 1, buf ^ 1);
    const int kv0 = cc * 64;

    // S^T = K * Q^T : 4 kv tiles of 16, K-dim = d (4 x 32)
    floatx4 sacc[4];
    #pragma unroll
    for (int t = 0; t < 4; ++t) sacc[t] = floatx4{0.f, 0.f, 0.f, 0.f};
    #pragma unroll
    for (int kk = 0; kk < 4; ++kk) {
      const int pc = ((kk << 2) + quad) ^ lr;
      #pragma unroll
      for (int t = 0; t < 4; ++t) {
        bf16x8 kf = *(const bf16x8*)(&Kb[buf][(t * 16 + lr) * 128 + pc * 8]);
        sacc[t] = __builtin_amdgcn_mfma_f32_16x16x32_bf16(kf, qf[kk], sacc[t], 0, 0, 0);
      }
    }

    // causal mask (diagonal chunk only)
    if (cc == nch - 1) {
      #pragma unroll
      for (int t = 0; t < 4; ++t)
        #pragma unroll
        for (int r = 0; r < 4; ++r) {
          int kv = kv0 + t * 16 + quad * 4 + r;
          if (kv > qrow_g) sacc[t][r] = NEG_BIG;
        }
    }

    // row max (16 regs + 2 cross-quad shuffles), then scale once
    float mx = sacc[0][0];
    #pragma unroll
    for (int t = 0; t < 4; ++t)
      #pragma unroll
      for (int r = 0; r < 4; ++r) mx = fmaxf(mx, sacc[t][r]);
    mx = fmaxf(mx, __shfl_xor(mx, 16, 64));
    mx = fmaxf(mx, __shfl_xor(mx, 32, 64));
    const float mn = fmaxf(m_r, mx * scale);
    const float alpha = __expf(m_r - mn);

    // p = exp(s*scale - mn); pack; wave-private swizzled LDS; row sum
    float lc = 0.f;
    #pragma unroll
    for (int t = 0; t < 4; ++t) {
      bf16x4 pk;
      #pragma unroll
      for (int r = 0; r < 4; ++r) {
        float p = __expf(fmaf(sacc[t][r], scale, -mn));
        lc += p;
        pk[r] = (bf16_t)p;
      }
      int pw = lr * 64 + (((2 * t + (quad >> 1)) ^ (lr & 7)) << 3) + (quad & 1) * 4;
      *(bf16x4*)(pmine + pw) = pk;
    }
    lc += __shfl_xor(lc, 16, 64);
    lc += __shfl_xor(lc, 32, 64);
    l_r = l_r * alpha + lc;
    m_r = mn;

    // O^T = O^T*alpha + V^T * P^T
    #pragma unroll
    for (int t = 0; t < 8; ++t)
      #pragma unroll
      for (int r = 0; r < 4; ++r) o[t][r] *= alpha;
    #pragma unroll
    for (int ks = 0; ks < 2; ++ks) {
      int prd = lr * 64 + (((ks * 4 + quad) ^ (lr & 7)) << 3);
      bf16x8 pf = *(const bf16x8*)(pmine + prd);
      #pragma unroll
      for (int t = 0; t < 8; ++t) {
        int pc = (ks * 4 + quad) ^ (lr & 7);
        bf16x8 vf = *(const bf16x8*)(&Vb[buf][(t * 16 + lr) * 64 + pc * 8]);
        o[t] = __builtin_amdgcn_mfma_f32_16x16x32_bf16(vf, pf, o[t], 0, 0, 0);
      }
    }
  }

  const float inv = 1.0f / l_r;
  bf16_t* crow = ctx + (size_t)qrow_g * HIDN + h * DH;
  #pragma unroll
  for (int t = 0; t < 8; ++t) {
    bf16x4 ov;
    #pragma unroll
    for (int r = 0; r < 4; ++r) ov[r] = (bf16_t)(o[t][r] * inv);
    *(bf16x4*)(crow + t * 16 + quad * 4) = ov;
  }
}

extern "C" void kernel_launch(void* const* d_in, const int* in_sizes, int n_in,
                              void* d_out, int out_size, void* d_ws, size_t ws_size,
                              hipStream_t stream)
{
  const float* xf   = (const float*)d_in[0];
  const float* Wqf  = (const float*)d_in[1];
  const float* Wkf  = (const float*)d_in[2];
  const float* Wvf  = (const float*)d_in[3];
  const float* Wof  = (const float*)d_in[4];
  const float* cosT = (const float*)d_in[5];
  const float* sinT = (const float*)d_in[6];
  float* out = (float*)d_out;

  char* ws = (char*)d_ws;
  const size_t MB = 1u << 20;
  bf16_t* xc  = (bf16_t*)(ws);              // 8 MB
  bf16_t* Wqc = (bf16_t*)(ws + 8  * MB);    // 8 MB
  bf16_t* Wkc = (bf16_t*)(ws + 16 * MB);    // 4 MB
  bf16_t* Wvc = (bf16_t*)(ws + 20 * MB);    // 4 MB
  bf16_t* Woc = (bf16_t*)(ws + 24 * MB);    // 8 MB
  bf16_t* qb  = (bf16_t*)(ws + 32 * MB);    // 8 MB
  bf16_t* kb  = (bf16_t*)(ws + 40 * MB);    // 4 MB
  bf16_t* vtb = (bf16_t*)(ws + 44 * MB);    // 4 MB
  bf16_t* ctx = (bf16_t*)(ws + 48 * MB);    // 8 MB

  hipLaunchKernelGGL(cvt_all_kernel, dim3(4096), dim3(256), 0, stream,
                     xf, Wqf, Wkf, Wvf, Wof, xc, Wqc, Wkc, Wvc, Woc);
  hipLaunchKernelGGL(gemm_qkv_kernel, dim3(16, 32), dim3(256), 0, stream,
                     xc, Wqc, Wkc, Wvc, qb, kb, vtb, cosT, sinT);
  hipLaunchKernelGGL(attn_kernel, dim3(512), dim3(256), 0, stream,
                     qb, kb, vtb, ctx);
  hipLaunchKernelGGL(gemm_out_kernel, dim3(16, 16), dim3(256), 0, stream,
                     ctx, Woc, out);
}